// Round 3
// baseline (734.662 us; speedup 1.0000x reference)
//
#include <hip/hip_runtime.h>
#include <math.h>

#define BATCH 64
#define IC 18
#define OC 32
#define H 224
#define W 224
#define ROWS_PER_BLOCK 8
#define NBLK_ROWS (H / ROWS_PER_BLOCK)   // 28
#define LDSW 232   // row pitch (floats)
#define XOFF 4     // left halo (col -1) at 3, cols 0..223 at 4..227, right halo at 228
#define NUM_L2 9

// ---------------------------------------------------------------------------
// Kernel A: fused conv3x3(18->32, SAME) + bias + ReLU + global-sum-pool.
// Grid: 64 batches x 28 row-blocks. Block: 256 threads.
//   tx  = tid & 31  -> output cols [7*tx, 7*tx+7)
//   toc = tid >> 5  -> ocs  [4*toc, 4*toc+4)
// Rotating 3-row LDS window keyed by (global_row % 3); one new row per
// iteration is prefetched to registers during compute and written after the
// barrier. Each thread keeps a 4x7 fp32 conv register tile, applies ReLU,
// accumulates per-oc pooling partials, shfl-reduces, one atomicAdd per (b,oc).
// ---------------------------------------------------------------------------
__global__ __launch_bounds__(256, 2)
void conv_pool_kernel(const float* __restrict__ x,
                      const float* __restrict__ conv_w,
                      const float* __restrict__ conv_b,
                      float* __restrict__ gsum) {
    __shared__ float xt[IC * 3 * LDSW];     // 12528 f = 50112 B
    __shared__ float wt[IC * 3 * 3 * OC];   //  5184 f = 20736 B  [ic][kh][kw][oc]

    const int tid = threadIdx.x;
    const int tx  = tid & 31;
    const int toc = tid >> 5;
    const int bid = blockIdx.x;
    const int b   = bid / NBLK_ROWS;
    const int rb  = bid % NBLK_ROWS;
    const int row0 = rb * ROWS_PER_BLOCK;

    // ---- prologue ----
    // weights -> LDS transposed: wt[(ic*9 + kh*3 + kw)*32 + oc]
    for (int i = tid; i < IC * 9 * OC; i += 256) {
        const int oc   = i & 31;
        const int rest = i >> 5;            // ic*9 + kh*3 + kw
        wt[i] = conv_w[oc * (IC * 9) + rest];
    }
    // zero the halo columns of all 54 (ic,slot) rows — they stay zero forever
    if (tid < IC * 3 * 2) {
        const int p    = tid >> 1;
        const int side = tid & 1;
        xt[p * LDSW + (side ? (W + XOFF) : (XOFF - 1))] = 0.f;
    }
    // load rows row0-1, row0, row0+1 into slots (gr mod 3)
    for (int r3 = 0; r3 < 3; ++r3) {
        const int gr   = row0 - 1 + r3;                 // may be -1 (zeros)
        const int slot = ((gr % 3) + 3) % 3;
        #pragma unroll
        for (int k = 0; k < 4; ++k) {
            const int li = tid + k * 256;               // 0..1007 cover 18ch x 56 f4
            if (li < IC * 56) {
                const int ic = li / 56;
                const int c4 = li % 56;
                float4 v = make_float4(0.f, 0.f, 0.f, 0.f);
                if (gr >= 0) {  // gr < H always true in prologue
                    v = *reinterpret_cast<const float4*>(
                            &x[((size_t)(b * IC + ic) * H + gr) * W + c4 * 4]);
                }
                *reinterpret_cast<float4*>(
                    &xt[(ic * 3 + slot) * LDSW + XOFF + c4 * 4]) = v;
            }
        }
    }
    __syncthreads();

    float bias[4];
    #pragma unroll
    for (int o = 0; o < 4; ++o) bias[o] = conv_b[toc * 4 + o];

    float pacc[4] = {0.f, 0.f, 0.f, 0.f};

    for (int ri = 0; ri < ROWS_PER_BLOCK; ++ri) {
        const int rc = row0 + ri;           // output row
        const bool do_pf = (ri < ROWS_PER_BLOCK - 1);

        // A: issue prefetch of row rc+2 into registers (latency hides under compute)
        const int gp = rc + 2;
        float4 pv[4];
        if (do_pf) {
            #pragma unroll
            for (int k = 0; k < 4; ++k) {
                const int li = tid + k * 256;
                pv[k] = make_float4(0.f, 0.f, 0.f, 0.f);
                if (li < IC * 56 && gp < H) {
                    const int ic = li / 56;
                    const int c4 = li % 56;
                    pv[k] = *reinterpret_cast<const float4*>(
                                &x[((size_t)(b * IC + ic) * H + gp) * W + c4 * 4]);
                }
            }
        }

        // B: compute conv for row rc from the 3 resident slots
        const int slt0 = (rc + 2) % 3;      // slot of row rc-1
        const int slt1 = rc % 3;            // slot of row rc
        const int slt2 = (rc + 1) % 3;      // slot of row rc+1

        float acc[4][7];
        #pragma unroll
        for (int o = 0; o < 4; ++o)
            #pragma unroll
            for (int p = 0; p < 7; ++p) acc[o][p] = 0.f;

        for (int ic = 0; ic < IC; ++ic) {
            const int icb = ic * 3;
            #pragma unroll
            for (int kh = 0; kh < 3; ++kh) {
                const int slot = (kh == 0) ? slt0 : (kh == 1) ? slt1 : slt2;
                const float* xr = &xt[(icb + slot) * LDSW + (XOFF - 1) + 7 * tx];
                float xv[9];
                #pragma unroll
                for (int j = 0; j < 9; ++j) xv[j] = xr[j];
                #pragma unroll
                for (int kw = 0; kw < 3; ++kw) {
                    const float4 wv = *reinterpret_cast<const float4*>(
                        &wt[((icb + kh) * 3 + kw) * OC + toc * 4]);
                    #pragma unroll
                    for (int p = 0; p < 7; ++p) {
                        const float xx = xv[p + kw];
                        acc[0][p] += wv.x * xx;
                        acc[1][p] += wv.y * xx;
                        acc[2][p] += wv.z * xx;
                        acc[3][p] += wv.w * xx;
                    }
                }
            }
        }

        // bias + relu + pool partial
        #pragma unroll
        for (int o = 0; o < 4; ++o) {
            float s = 0.f;
            #pragma unroll
            for (int p = 0; p < 7; ++p) s += fmaxf(acc[o][p] + bias[o], 0.f);
            pacc[o] += s;
        }

        // C: retire row rc-1's slot, install row rc+2
        __syncthreads();
        if (do_pf) {
            const int wslot = (rc + 2) % 3;  // == (rc-1) mod 3, the freed slot
            #pragma unroll
            for (int k = 0; k < 4; ++k) {
                const int li = tid + k * 256;
                if (li < IC * 56) {
                    const int ic = li / 56;
                    const int c4 = li % 56;
                    *reinterpret_cast<float4*>(
                        &xt[(ic * 3 + wslot) * LDSW + XOFF + c4 * 4]) = pv[k];
                }
            }
        }
        __syncthreads();
    }

    // reduce across the 32 col-threads of each oc-group (contiguous 32 lanes)
    #pragma unroll
    for (int o = 0; o < 4; ++o) {
        float v = pacc[o];
        #pragma unroll
        for (int s = 16; s > 0; s >>= 1) v += __shfl_down(v, s, 32);
        if (tx == 0) atomicAdd(&gsum[b * OC + toc * 4 + o], v);
    }
}

// ---------------------------------------------------------------------------
// Kernel B: head. g = gsum/50176 ; f = relu([g,pred] @ fc1_w^T + b1);
// logits = f @ fc2_w^T + b2 ; hierarchical mask from argmax(pred); softmax.
// One block, 64 threads (one per batch row). Trivial cost.
// ---------------------------------------------------------------------------
__global__ void head_kernel(const float* __restrict__ gsum,
                            const float* __restrict__ pred,
                            const float* __restrict__ fc1_w,
                            const float* __restrict__ fc1_b,
                            const float* __restrict__ fc2_w,
                            const float* __restrict__ fc2_b,
                            float* __restrict__ out) {
    const int b = threadIdx.x;
    if (b >= BATCH) return;

    float feat[34];
    const float inv = 1.f / (float)(H * W);
    #pragma unroll
    for (int c = 0; c < 32; ++c) feat[c] = gsum[b * 32 + c] * inv;
    feat[32] = pred[b * 2 + 0];
    feat[33] = pred[b * 2 + 1];

    float f[64];
    for (int j = 0; j < 64; ++j) {
        float s = fc1_b[j];
        #pragma unroll
        for (int k = 0; k < 34; ++k) s += feat[k] * fc1_w[j * 34 + k];
        f[j] = fmaxf(s, 0.f);
    }

    float l[NUM_L2];
    for (int c = 0; c < NUM_L2; ++c) {
        float s = fc2_b[c];
        #pragma unroll
        for (int j = 0; j < 64; ++j) s += f[j] * fc2_w[c * 64 + j];
        l[c] = s;
    }

    const int idx = (pred[b * 2 + 1] > pred[b * 2 + 0]) ? 1 : 0;  // argmax, first-max ties
    const int lo = idx ? 4 : 0;
    const int hi = idx ? 9 : 4;

    float m = -1e30f;
    for (int c = lo; c < hi; ++c) m = fmaxf(m, l[c]);
    float e[NUM_L2];
    float ssum = 0.f;
    for (int c = 0; c < NUM_L2; ++c) {
        const float v = (c >= lo && c < hi) ? expf(l[c] - m) : 0.f;
        e[c] = v;
        ssum += v;
    }
    const float rs = 1.f / ssum;
    for (int c = 0; c < NUM_L2; ++c) out[b * NUM_L2 + c] = e[c] * rs;
}

extern "C" void kernel_launch(void* const* d_in, const int* in_sizes, int n_in,
                              void* d_out, int out_size, void* d_ws, size_t ws_size,
                              hipStream_t stream) {
    const float* x      = (const float*)d_in[0];
    const float* pred   = (const float*)d_in[1];
    const float* conv_w = (const float*)d_in[2];
    const float* conv_b = (const float*)d_in[3];
    const float* fc1_w  = (const float*)d_in[4];
    const float* fc1_b  = (const float*)d_in[5];
    const float* fc2_w  = (const float*)d_in[6];
    const float* fc2_b  = (const float*)d_in[7];
    float* out  = (float*)d_out;
    float* gsum = (float*)d_ws;   // [64][32] pooling sums

    hipMemsetAsync(gsum, 0, BATCH * OC * sizeof(float), stream);
    conv_pool_kernel<<<BATCH * NBLK_ROWS, 256, 0, stream>>>(x, conv_w, conv_b, gsum);
    head_kernel<<<1, 64, 0, stream>>>(gsum, pred, fc1_w, fc1_b, fc2_w, fc2_b, out);
}

// Round 5
// 412.646 us; speedup vs baseline: 1.7804x; 1.7804x over previous
//
#include <hip/hip_runtime.h>
#include <math.h>

typedef _Float16 f16;
typedef _Float16 f16x2 __attribute__((ext_vector_type(2)));
typedef _Float16 f16x8 __attribute__((ext_vector_type(8)));
typedef float f32x16 __attribute__((ext_vector_type(16)));

#define BATCH 64
#define IC 18
#define OC 32
#define H 224
#define W 224
#define RSTRIP 28
#define NSTRIP 8              // 224 / 28
#define NITER (RSTRIP + 2)    // 30 input-row iterations (divisible by 3)
#define RECS 226              // records per slab buffer (record r <-> input col r-1)
#define RECW 24               // f16 per record (48 B): 0..17 ic, 18..19 patch, 20..23 pad
#define SLABF (RECS * RECW)
#define BSTRIDE 72            // B-matrix LDS row pitch (144 B: 16B-aligned, conflict-free)
#define NUM_L2 9

#define MF(a_, b_, c_) c_ = __builtin_amdgcn_mfma_f32_32x32x16_f16((a_), (b_), (c_), 0, 0, 0)

// ---------------------------------------------------------------------------
// Conv3x3(18->32, SAME) + bias + ReLU + global-sum-pool via implicit-GEMM MFMA.
// Grid: 64 batches x 8 row-strips (28 rows). Block: 448 threads = 7 waves,
// wave w owns output-pixel tile [32w, 32w+32) of the row.
// K' = 64 packed: [kw0: ic0..17 | kw2: ic16,17 | pad x4 | kw1: ic0..17 |
//                  pad x6 | kw2: ic0..15]  (pads masked by B=0; pads ZEROED
//                  in LDS once — NaN*0 would poison the MFMA accumulator).
// Record r (48 B) = f16 x[col r-1][ic0..17] ++ patch x[col r+1][ic16,17]
//  => A[p][k'] = slab[24p + k']: each 16-k' chunk is ONE aligned ds_read_b128,
//     and the stride-48B lane pattern hits all 8 bank-quads evenly (no conflict).
// Row-stationary: input row g feeds kh=0,1,2 into 3 rotating accumulators
// (out-rows g+1, g, g-1); retiring row -> bias+ReLU+pool into pacc.
// Staging: 2 threads per column, f16x8 b128 writes (T14 split: loads issued
// before the MFMA phase, LDS writes after).
// ---------------------------------------------------------------------------
__global__ __launch_bounds__(448, 2)
void conv_mfma_kernel(const float* __restrict__ x,
                      const float* __restrict__ conv_w,
                      const float* __restrict__ conv_b,
                      float* __restrict__ gsum) {
    __shared__ __align__(16) f16 slab[2][SLABF];      // 2 x 10848 B
    __shared__ __align__(16) f16 Bw[3 * 32 * BSTRIDE]; // 13824 B [kh][oc][k' padded]

    const int tid = threadIdx.x;
    const int l   = tid & 63;
    const int wv  = tid >> 6;        // 0..6 : px tile
    const int lm  = l & 31;          // A-row (px) / B-col (oc) / D-col (oc)
    const int lh  = l >> 5;          // k-half
    const int b     = blockIdx.x >> 3;
    const int strip = blockIdx.x & 7;
    const int r0    = strip * RSTRIP;

    // staging role: 2 threads per column; h=0 -> ch 0..7, h=1 -> ch 8..17
    const int c = tid >> 1;          // 0..223
    const int h = tid & 1;
    const size_t plane = (size_t)H * W;
    const float* xb = x + ((size_t)b * IC + 8 * h) * plane + c;

    // ---- prologue: B matrix [kh][oc][k'] ----
    for (int idx = tid; idx < 3 * 32 * 64; idx += 448) {
        const int kh = idx >> 11;
        const int oc = (idx >> 6) & 31;
        const int kp = idx & 63;
        int kw = 0, ic = 0, valid = 1;
        if (kp < 18)      { kw = 0; ic = kp; }
        else if (kp < 20) { kw = 2; ic = 16 + (kp - 18); }
        else if (kp < 24) { valid = 0; }
        else if (kp < 42) { kw = 1; ic = kp - 24; }
        else if (kp < 48) { valid = 0; }
        else              { kw = 2; ic = kp - 48; }
        Bw[(kh * 32 + oc) * BSTRIDE + kp] =
            (f16)(valid ? conv_w[oc * 162 + ic * 9 + kh * 3 + kw] : 0.f);
    }
    // zero pad slots 20..23 of EVERY record, both buffers (NaN-poison safety;
    // staging never writes them, B=0 masks them, but A must be finite)
    for (int i = tid; i < 2 * RECS; i += 448) {
        const int buf = (i >= RECS) ? 1 : 0;
        const int rec = buf ? (i - RECS) : i;
        *reinterpret_cast<float2*>(&slab[buf][rec * RECW + 20]) = make_float2(0.f, 0.f);
    }
    // zero slots staging never covers: rec0 main 0..17 (col -1 halo),
    // rec224 patch 18..19 (col 225 OOB), rec225 slots 0..19 (col 224 halo).
    // Disjoint from all staging writes -> no race.
    for (int i = tid; i < 2 * 20; i += 448) {
        const int buf = (i >= 20) ? 1 : 0;
        const int k = buf ? (i - 20) : i;
        f16x2 z2; z2[0] = (f16)0.f; z2[1] = (f16)0.f;
        if (k < 9)
            *reinterpret_cast<f16x2*>(&slab[buf][0 * RECW + 2 * k]) = z2;
        else if (k == 9)
            *reinterpret_cast<f16x2*>(&slab[buf][224 * RECW + 18]) = z2;
        else
            *reinterpret_cast<f16x2*>(&slab[buf][225 * RECW + 2 * (k - 10)]) = z2;
    }

    auto STAGE_LOAD = [&](int grow, float* sv) {
        const bool inr = (grow >= 0) && (grow < H);
        if (inr) {
            const float* p = xb + (size_t)grow * W;
            #pragma unroll
            for (int j = 0; j < 8; ++j) sv[j] = p[j * plane];
            if (h) { sv[8] = p[8 * plane]; sv[9] = p[9 * plane]; }
            else   { sv[8] = 0.f; sv[9] = 0.f; }
        } else {
            #pragma unroll
            for (int j = 0; j < 10; ++j) sv[j] = 0.f;
        }
    };
    auto STAGE_WRITE = [&](int buf, const float* sv) {
        f16* sw = &slab[buf][0];
        f16x8 v;
        #pragma unroll
        for (int j = 0; j < 8; ++j) v[j] = (f16)sv[j];
        *reinterpret_cast<f16x8*>(&sw[(c + 1) * RECW + 8 * h]) = v;   // slots 0..7 / 8..15
        if (h) {
            f16x2 p2; p2[0] = (f16)sv[8]; p2[1] = (f16)sv[9];         // ic 16,17 of col c
            *reinterpret_cast<f16x2*>(&sw[(c + 1) * RECW + 16]) = p2; // main slots 16,17
            f16x2 pp = p2;
            if (c == 0) { pp[0] = (f16)0.f; pp[1] = (f16)0.f; }       // rec223 patch = OOB col 224
            const int prec = (c == 0) ? 223 : (c - 1);                // rec r patch = x[col r+1]
            *reinterpret_cast<f16x2*>(&sw[prec * RECW + 18]) = pp;
        }
    };

    // stage input row r0-1 into slab[0]
    {
        float sv[10];
        STAGE_LOAD(r0 - 1, sv);
        STAGE_WRITE(0, sv);
    }
    __syncthreads();

    // B fragments to registers, once: bfr[kh][chunk]
    f16x8 bfr[3][4];
    #pragma unroll
    for (int kh = 0; kh < 3; ++kh)
        #pragma unroll
        for (int cc = 0; cc < 4; ++cc)
            bfr[kh][cc] = *reinterpret_cast<const f16x8*>(
                &Bw[(kh * 32 + lm) * BSTRIDE + 16 * cc + 8 * lh]);

    const float bias = conv_b[lm];
    float pacc = 0.f;
    f32x16 acc0, acc1, acc2;
    #pragma unroll
    for (int i = 0; i < 16; ++i) { acc0[i] = 0.f; acc1[i] = 0.f; acc2[i] = 0.f; }

    const int abase = RECW * (32 * wv + lm) + 8 * lh;   // f16 index of A chunk 0

    // ITER(gi): input row g = r0-1+gi from slab[gi&1].
    // kh0 -> out-row g+1 (aK0), kh1 -> g (aK1), kh2 -> g-1 (aK2, retires).
    auto ITER = [&](int gi, f32x16& aK0, f32x16& aK1, f32x16& aK2) {
        const int cur = gi & 1;
        const bool do_stage = (gi != NITER - 1);
        float sv[10];
        if (do_stage) STAGE_LOAD(r0 + gi, sv);          // issue early (T14)

        const f16* sb = &slab[cur][0];
        const f16x8 a0 = *reinterpret_cast<const f16x8*>(&sb[abase]);
        const f16x8 a1 = *reinterpret_cast<const f16x8*>(&sb[abase + 16]);
        const f16x8 a2 = *reinterpret_cast<const f16x8*>(&sb[abase + 32]);
        const f16x8 a3 = *reinterpret_cast<const f16x8*>(&sb[abase + 48]);
        MF(a0, bfr[0][0], aK0); MF(a1, bfr[0][1], aK0); MF(a2, bfr[0][2], aK0); MF(a3, bfr[0][3], aK0);
        MF(a0, bfr[1][0], aK1); MF(a1, bfr[1][1], aK1); MF(a2, bfr[1][2], aK1); MF(a3, bfr[1][3], aK1);
        MF(a0, bfr[2][0], aK2); MF(a1, bfr[2][1], aK2); MF(a2, bfr[2][2], aK2); MF(a3, bfr[2][3], aK2);

        // retire out-row r0-2+gi (register-only; also covers load latency)
        if (gi >= 2) {
            float s = 0.f;
            #pragma unroll
            for (int i = 0; i < 16; ++i) s += fmaxf(aK2[i] + bias, 0.f);
            pacc += s;
        }
        #pragma unroll
        for (int i = 0; i < 16; ++i) aK2[i] = 0.f;

        if (do_stage) STAGE_WRITE(cur ^ 1, sv);         // write late (waits vmcnt)
        __syncthreads();                                // one barrier per iteration
    };

    for (int g3 = 0; g3 < NITER; g3 += 3) {             // static acc rotation (rule #20)
        ITER(g3 + 0, acc2, acc1, acc0);
        ITER(g3 + 1, acc0, acc2, acc1);
        ITER(g3 + 2, acc1, acc0, acc2);
    }

    // lanes l and l^32 hold the two px-halves of the same oc
    pacc += __shfl_xor(pacc, 32);
    if (l < 32) atomicAdd(&gsum[b * OC + lm], pacc);
}

// ---------------------------------------------------------------------------
// Head: g = gsum/50176; f = relu([g,pred] @ fc1_w^T + b1);
// logits = f @ fc2_w^T + b2; hierarchical mask from argmax(pred); softmax.
// ---------------------------------------------------------------------------
__global__ void head_kernel(const float* __restrict__ gsum,
                            const float* __restrict__ pred,
                            const float* __restrict__ fc1_w,
                            const float* __restrict__ fc1_b,
                            const float* __restrict__ fc2_w,
                            const float* __restrict__ fc2_b,
                            float* __restrict__ out) {
    const int b = threadIdx.x;
    if (b >= BATCH) return;

    float feat[34];
    const float inv = 1.f / (float)(H * W);
    #pragma unroll
    for (int c = 0; c < 32; ++c) feat[c] = gsum[b * 32 + c] * inv;
    feat[32] = pred[b * 2 + 0];
    feat[33] = pred[b * 2 + 1];

    float f[64];
    for (int j = 0; j < 64; ++j) {
        float s = fc1_b[j];
        #pragma unroll
        for (int k = 0; k < 34; ++k) s += feat[k] * fc1_w[j * 34 + k];
        f[j] = fmaxf(s, 0.f);
    }

    float lg[NUM_L2];
    for (int c = 0; c < NUM_L2; ++c) {
        float s = fc2_b[c];
        #pragma unroll
        for (int j = 0; j < 64; ++j) s += f[j] * fc2_w[c * 64 + j];
        lg[c] = s;
    }

    const int idx = (pred[b * 2 + 1] > pred[b * 2 + 0]) ? 1 : 0;  // first-max ties
    const int lo = idx ? 4 : 0;
    const int hi = idx ? 9 : 4;

    float m = -1e30f;
    for (int c = lo; c < hi; ++c) m = fmaxf(m, lg[c]);
    float e[NUM_L2];
    float ssum = 0.f;
    for (int c = 0; c < NUM_L2; ++c) {
        const float v = (c >= lo && c < hi) ? expf(lg[c] - m) : 0.f;
        e[c] = v;
        ssum += v;
    }
    const float rs = 1.f / ssum;
    for (int c = 0; c < NUM_L2; ++c) out[b * NUM_L2 + c] = e[c] * rs;
}

extern "C" void kernel_launch(void* const* d_in, const int* in_sizes, int n_in,
                              void* d_out, int out_size, void* d_ws, size_t ws_size,
                              hipStream_t stream) {
    const float* x      = (const float*)d_in[0];
    const float* pred   = (const float*)d_in[1];
    const float* conv_w = (const float*)d_in[2];
    const float* conv_b = (const float*)d_in[3];
    const float* fc1_w  = (const float*)d_in[4];
    const float* fc1_b  = (const float*)d_in[5];
    const float* fc2_w  = (const float*)d_in[6];
    const float* fc2_b  = (const float*)d_in[7];
    float* out  = (float*)d_out;
    float* gsum = (float*)d_ws;   // [64][32] pooling sums

    hipMemsetAsync(gsum, 0, BATCH * OC * sizeof(float), stream);
    conv_mfma_kernel<<<BATCH * NSTRIP, 448, 0, stream>>>(x, conv_w, conv_b, gsum);
    head_kernel<<<1, 64, 0, stream>>>(gsum, pred, fc1_w, fc1_b, fc2_w, fc2_b, out);
}

// Round 7
// 365.873 us; speedup vs baseline: 2.0080x; 1.1278x over previous
//
#include <hip/hip_runtime.h>
#include <math.h>

typedef _Float16 f16;
typedef _Float16 f16x2 __attribute__((ext_vector_type(2)));
typedef _Float16 f16x8 __attribute__((ext_vector_type(8)));
typedef float f32x16 __attribute__((ext_vector_type(16)));

#define BATCH 64
#define IC 18
#define OC 32
#define H 224
#define W 224
#define RSTRIP 28
#define NSTRIP 8              // 224/28
#define NTILE 7               // 224/32
#define WPB 4                 // waves per block
#define KPW (NTILE * NSTRIP)  // 56 wave-units per batch
#define UNITS (BATCH * KPW)   // 3584 wave-units
#define NBLOCK (UNITS / WPB)  // 896 blocks
#define RECS 34               // records per row-slot (cols 32t-1 .. 32t+32)
#define RECW 24               // f16 per record (48 B): 0..17 ic, 18..19 patch, 20..23 pad
#define SLOTF (RECS * RECW)   // 816 f16 per row-slot
#define BSTRIDE 72            // B-matrix LDS pitch (144 B, conflict-free)
#define NUM_L2 9

#define MF(a_, b_, c_) c_ = __builtin_amdgcn_mfma_f32_32x32x16_f16((a_), (b_), (c_), 0, 0, 0)

// ---------------------------------------------------------------------------
// Conv3x3(18->32, SAME) + bias + ReLU + global-sum-pool, implicit-GEMM MFMA.
// Grid: 896 blocks x 256 thr = 3584 WAVE-UNITS; wave = (b, 32-col tile t,
// 28-row strip s). Waves are fully independent after the one weight barrier:
// each streams a private 4-slot rotating LDS window (slot = row & 3), no
// __syncthreads in the main loop, no atomics (per-wave partial to d_ws).
// K' = 64 packing (verified round-5): [kw0 ic0..17 | kw2 ic16,17 | pad4 |
// kw1 ic0..17 | pad6 | kw2 ic0..15]; record p main = x[32t+p-1][ic0..17],
// patch = x[32t+p+1][ic16,17]; A[px] = one aligned b128 per 16-k' chunk at
// f16 index 24*px + 8*lh + 16*c (stride-48B lane pattern = conflict-free).
// Output-stationary: row r = A(r-1)*bfr[0] + A(r)*bfr[1] + A(r+1)*bfr[2]
// into ONE f32x16 acc (low VGPR -> 4 waves/SIMD at <=128 regs).
// ---------------------------------------------------------------------------
__global__ __launch_bounds__(256, 4)
void conv_mfma_kernel(const float* __restrict__ x,
                      const float* __restrict__ conv_w,
                      const float* __restrict__ conv_b,
                      float* __restrict__ part) {
    __shared__ __align__(16) f16 slab[WPB][4][SLOTF];   // 26112 B
    __shared__ __align__(16) f16 Bw[3 * 32 * BSTRIDE];  // 13824 B

    const int tid = threadIdx.x;
    const int l   = tid & 63;
    const int wv  = tid >> 6;
    const int lm  = l & 31;          // A-row(px) / B&D col(oc)
    const int lh  = l >> 5;          // k-half

    const int unit = blockIdx.x * WPB + wv;
    const int b    = unit / KPW;
    const int rem  = unit - b * KPW;
    const int t    = rem % NTILE;
    const int s    = rem / NTILE;
    const int r0   = s * RSTRIP;
    const int col0 = t * 32 - 1;     // column of record 0

    // ---- weights -> Bw[kh][oc][k'] (all threads, one barrier) ----
    for (int idx = tid; idx < 3 * 32 * 64; idx += 256) {
        const int kh = idx >> 11;
        const int oc = (idx >> 6) & 31;
        const int kp = idx & 63;
        int kw = 0, ic = 0, valid = 1;
        if (kp < 18)      { kw = 0; ic = kp; }
        else if (kp < 20) { kw = 2; ic = 16 + (kp - 18); }
        else if (kp < 24) { valid = 0; }
        else if (kp < 42) { kw = 1; ic = kp - 24; }
        else if (kp < 48) { valid = 0; }
        else              { kw = 2; ic = kp - 48; }
        Bw[(kh * 32 + oc) * BSTRIDE + kp] =
            (f16)(valid ? conv_w[oc * 162 + ic * 9 + kh * 3 + kw] : 0.f);
    }

    // ---- per-wave: zero the pad slots of all 4 slots (staging never writes
    // them; they ARE read by A chunks and must be finite — B=0 masks them) ----
    for (int i = l; i < 4 * RECS; i += 64) {
        const int sl  = i / RECS;
        const int rec = i - sl * RECS;
        f16* q = &slab[wv][sl][rec * RECW];
        f16x2 z2; z2[0] = (f16)0.f; z2[1] = (f16)0.f;
        *reinterpret_cast<f16x2*>(&q[20]) = z2;
        *reinterpret_cast<f16x2*>(&q[22]) = z2;
        if (rec >= 32) *reinterpret_cast<f16x2*>(&q[18]) = z2;  // recs 32,33: patch unread->0
    }
    __syncthreads();   // Bw ready (also covers pad zeroing trivially)

    // ---- staging roles ----
    const int p   = l >> 1;            // record 0..31
    const int hh  = l & 1;             // 0: ic0..7 ; 1: ic8..17
    const int col = col0 + p;          // main column of record p
    const bool colok = (col >= 0) & (col < W);
    const size_t plane = (size_t)H * W;
    const float* xb = x + ((size_t)b * IC + 8 * hh) * plane + col;
    // extras: lanes 0..3 also stage records 32,33 (cols 32t+31, 32t+32)
    const int er   = 32 + (l >> 1);    // valid for l<4
    const int ecol = col0 + er;
    const bool eok = (l < 4) & (ecol < W);
    const float* xe = x + ((size_t)b * IC + 8 * hh) * plane + ecol;

    auto STAGE_LOAD = [&](int g, float* sv, float* sve) {
        const bool rok = (g >= 0) & (g < H);
        if (rok & colok) {
            const float* q = xb + (size_t)g * W;
            #pragma unroll
            for (int j = 0; j < 8; ++j) sv[j] = q[j * plane];
            if (hh) { sv[8] = q[8 * plane]; sv[9] = q[9 * plane]; }
            else    { sv[8] = 0.f; sv[9] = 0.f; }
        } else {
            #pragma unroll
            for (int j = 0; j < 10; ++j) sv[j] = 0.f;
        }
        if (l < 4) {
            if (rok & eok) {
                const float* q = xe + (size_t)g * W;
                #pragma unroll
                for (int j = 0; j < 8; ++j) sve[j] = q[j * plane];
                if (hh) { sve[8] = q[8 * plane]; sve[9] = q[9 * plane]; }
                else    { sve[8] = 0.f; sve[9] = 0.f; }
            } else {
                #pragma unroll
                for (int j = 0; j < 10; ++j) sve[j] = 0.f;
            }
        }
    };
    auto STAGE_WRITE = [&](int slot, const float* sv, const float* sve) {
        f16* sw = &slab[wv][slot][0];
        f16x8 v;
        #pragma unroll
        for (int j = 0; j < 8; ++j) v[j] = (f16)sv[j];
        *reinterpret_cast<f16x8*>(&sw[p * RECW + 8 * hh]) = v;  // slots 0..7 / 8..15
        if (hh) {
            f16x2 c2; c2[0] = (f16)sv[8]; c2[1] = (f16)sv[9];   // ic16,17 of col C_p
            *reinterpret_cast<f16x2*>(&sw[p * RECW + 16]) = c2;
            if (p >= 2)                                          // patch of record p-2
                *reinterpret_cast<f16x2*>(&sw[(p - 2) * RECW + 18]) = c2;
        }
        if (l < 4) {
            f16x8 w8;
            #pragma unroll
            for (int j = 0; j < 8; ++j) w8[j] = (f16)sve[j];
            *reinterpret_cast<f16x8*>(&sw[er * RECW + 8 * hh]) = w8;
            if (hh) {
                f16x2 e2; e2[0] = (f16)sve[8]; e2[1] = (f16)sve[9];
                *reinterpret_cast<f16x2*>(&sw[er * RECW + 16]) = e2;
                *reinterpret_cast<f16x2*>(&sw[(er - 2) * RECW + 18]) = e2; // patches 30,31
            }
        }
    };

    // ---- prologue: stage input rows r0-1, r0, r0+1 into slots (g & 3) ----
    for (int g = r0 - 1; g <= r0 + 1; ++g) {
        float sv[10], sve[10];
        STAGE_LOAD(g, sv, sve);
        STAGE_WRITE(g & 3, sv, sve);
    }

    // ---- B fragments to registers (once) ----
    f16x8 bfr[3][4];
    #pragma unroll
    for (int kh = 0; kh < 3; ++kh)
        #pragma unroll
        for (int cc = 0; cc < 4; ++cc)
            bfr[kh][cc] = *reinterpret_cast<const f16x8*>(
                &Bw[(kh * 32 + lm) * BSTRIDE + 16 * cc + 8 * lh]);

    const float bias = conv_b[lm];
    float pacc = 0.f;
    f32x16 acc;
    #pragma unroll
    for (int i = 0; i < 16; ++i) acc[i] = 0.f;

    const int abase = RECW * lm + 8 * lh;   // f16 offset of A chunk 0 within a slot

    // ---- main loop: 28 output rows, wave-private, barrier-free ----
    for (int r = r0; r < r0 + RSTRIP; ++r) {
        const bool do_stage = (r != r0 + RSTRIP - 1);
        float sv[10], sve[10];
        if (do_stage) STAGE_LOAD(r + 2, sv, sve);    // issue loads early (T14)

        #pragma unroll
        for (int kh = 0; kh < 3; ++kh) {             // input rows r-1, r, r+1
            const f16* sb = &slab[wv][(r - 1 + kh) & 3][0];
            const f16x8 a0 = *reinterpret_cast<const f16x8*>(&sb[abase]);
            const f16x8 a1 = *reinterpret_cast<const f16x8*>(&sb[abase + 16]);
            const f16x8 a2 = *reinterpret_cast<const f16x8*>(&sb[abase + 32]);
            const f16x8 a3 = *reinterpret_cast<const f16x8*>(&sb[abase + 48]);
            MF(a0, bfr[kh][0], acc); MF(a1, bfr[kh][1], acc);
            MF(a2, bfr[kh][2], acc); MF(a3, bfr[kh][3], acc);
        }

        float ssum = 0.f;
        #pragma unroll
        for (int i = 0; i < 16; ++i) ssum += fmaxf(acc[i] + bias, 0.f);
        pacc += ssum;
        #pragma unroll
        for (int i = 0; i < 16; ++i) acc[i] = 0.f;

        if (do_stage) STAGE_WRITE((r + 2) & 3, sv, sve);  // write late (after vmcnt)
    }

    // lanes l and l^32 hold the two px-halves of the same oc
    pacc += __shfl_xor(pacc, 32);
    if (l < 32) part[((size_t)b * KPW + rem) * 32 + lm] = pacc;  // private slot, no atomic
}

// ---------------------------------------------------------------------------
// Head: one block per batch row. feat = [sum(part)/50176, pred];
// f = relu(feat @ fc1_w^T + b1); logits = f @ fc2_w^T + b2;
// hierarchical mask from argmax(pred); softmax.
// ---------------------------------------------------------------------------
__global__ void head_kernel(const float* __restrict__ part,
                            const float* __restrict__ pred,
                            const float* __restrict__ fc1_w,
                            const float* __restrict__ fc1_b,
                            const float* __restrict__ fc2_w,
                            const float* __restrict__ fc2_b,
                            float* __restrict__ out) {
    __shared__ float feat[34];
    __shared__ float fsh[64];
    __shared__ float lsh[NUM_L2];
    const int b = blockIdx.x;
    const int tI = threadIdx.x;

    if (tI < 32) {
        float sres = 0.f;
        const float* pp = part + (size_t)b * KPW * 32 + tI;
        for (int k = 0; k < KPW; ++k) sres += pp[k * 32];
        feat[tI] = sres * (1.f / (float)(H * W));
    } else if (tI < 34) {
        feat[tI] = pred[b * 2 + (tI - 32)];
    }
    __syncthreads();

    {
        float sum = fc1_b[tI];
        #pragma unroll
        for (int k = 0; k < 34; ++k) sum += feat[k] * fc1_w[tI * 34 + k];
        fsh[tI] = fmaxf(sum, 0.f);
    }
    __syncthreads();

    if (tI < NUM_L2) {
        float sum = fc2_b[tI];
        #pragma unroll
        for (int j = 0; j < 64; ++j) sum += fsh[j] * fc2_w[tI * 64 + j];
        lsh[tI] = sum;
    }
    __syncthreads();

    if (tI == 0) {
        const int idx = (pred[b * 2 + 1] > pred[b * 2 + 0]) ? 1 : 0;  // first-max ties
        const int lo = idx ? 4 : 0;
        const int hi = idx ? 9 : 4;
        float m = -1e30f;
        for (int c = lo; c < hi; ++c) m = fmaxf(m, lsh[c]);
        float e[NUM_L2];
        float ssum = 0.f;
        for (int c = 0; c < NUM_L2; ++c) {
            const float v = (c >= lo && c < hi) ? expf(lsh[c] - m) : 0.f;
            e[c] = v;
            ssum += v;
        }
        const float rs = 1.f / ssum;
        for (int c = 0; c < NUM_L2; ++c) out[b * NUM_L2 + c] = e[c] * rs;
    }
}

extern "C" void kernel_launch(void* const* d_in, const int* in_sizes, int n_in,
                              void* d_out, int out_size, void* d_ws, size_t ws_size,
                              hipStream_t stream) {
    const float* x      = (const float*)d_in[0];
    const float* pred   = (const float*)d_in[1];
    const float* conv_w = (const float*)d_in[2];
    const float* conv_b = (const float*)d_in[3];
    const float* fc1_w  = (const float*)d_in[4];
    const float* fc1_b  = (const float*)d_in[5];
    const float* fc2_w  = (const float*)d_in[6];
    const float* fc2_b  = (const float*)d_in[7];
    float* out  = (float*)d_out;
    float* part = (float*)d_ws;   // [64][56][32] per-wave pool partials (fully overwritten)

    conv_mfma_kernel<<<NBLOCK, 256, 0, stream>>>(x, conv_w, conv_b, part);
    head_kernel<<<BATCH, 64, 0, stream>>>(part, pred, fc1_w, fc1_b, fc2_w, fc2_b, out);
}